// Round 11
// baseline (81.006 us; speedup 1.0000x reference)
//
#include <hip/hip_runtime.h>
#include <math.h>

#define HH 96
#define WW 320
#define NP 8

typedef _Float16 half8_t  __attribute__((ext_vector_type(8)));
typedef _Float16 half4_t  __attribute__((ext_vector_type(4)));
typedef float    floatx16 __attribute__((ext_vector_type(16)));

struct ShiftInfo {
    int   s0[NP];
    float wa[NP];
    float wb[NP];
    int   rows[16];
};

// async global->LDS, 16B per lane, dest = wave-uniform base + lane*16
__device__ __forceinline__ void gl_lds16(const _Float16* g, _Float16* l) {
    __builtin_amdgcn_global_load_lds(
        (const __attribute__((address_space(1))) void*)g,
        (__attribute__((address_space(3))) void*)l, 16, 0, 0);
}

// ---------------------------------------------------------------------------
// prep: blockIdx.x < 768 -> transpose+cvt one (b,y,x-half) strip of X into Xt
//       blockIdx.x >= 768 -> weight cvt to MFMA-fragment-native layout.
// ---------------------------------------------------------------------------
__global__ __launch_bounds__(256) void prep_kernel(
    const float* __restrict__ X, const float* __restrict__ W1,
    const float* __restrict__ W2, _Float16* __restrict__ Xt,
    _Float16* __restrict__ Wf)
{
    __shared__ __align__(16) _Float16 Ls[64 * 163];
    const int bx = blockIdx.x, t = threadIdx.x;
    if (bx < 768) {
        const int r = bx >> 1, xh = bx & 1;
        const int y = r % HH, b = r / HH;
        const int xbase = xh * 160;
        for (int u = t; u < 64 * 40; u += 256) {
            int ci = u / 40;
            int xi = (u - ci * 40) * 4;
            float4 v = *(const float4*)&X[((size_t)(b * 64 + ci) * HH + y) * WW + xbase + xi];
            half4_t hv = { (_Float16)v.x, (_Float16)v.y, (_Float16)v.z, (_Float16)v.w };
            *(half4_t*)&Ls[ci * 163 + xi] = hv;
        }
        __syncthreads();
        const int ci8 = t & 7, xg = t >> 3;
        for (int it = 0; it < 5; ++it) {
            int x = xg + 32 * it;
            half8_t o;
#pragma unroll
            for (int j = 0; j < 8; ++j) o[j] = Ls[(ci8 * 8 + j) * 163 + x];
            *(half8_t*)&Xt[((size_t)(b * HH + y) * WW + xbase + x) * 64 + ci8 * 8] = o;
        }
    } else {
        const int k = bx - 768;                  // 0..17
        const int layer = k / 9, pos = k - layer * 9;
        const float* Ws = layer ? W2 : W1;
        _Float16* Wd = Wf + layer * 36864 + pos * 4096;
        for (int u = t; u < 4096; u += 256) {
            int mt  = u >> 11;
            int ks  = (u >> 9) & 3;
            int i31 = (u >> 4) & 31;
            int h   = (u >> 3) & 1;
            int j   = u & 7;
            int co  = mt * 32 + i31;
            int ci  = ks * 16 + h * 8 + j;
            Wd[u] = (_Float16)Ws[((size_t)co * 64 + ci) * 9 + pos];
        }
    }
}

// ---------------------------------------------------------------------------
// MFMA implicit-GEMM conv, merged grid (5, 24, 4) = 480 blocks (single
// dispatch wave at 2 blocks/CU).
// Weights in VGPRs, 3 pos (= one ky row) at a time: 24 fragments = 96 VGPR
// loaded straight from global (L2/L1-resident, shared chip-wide).  Inner
// loop reads ONLY X from LDS: 8 ds_read_b128 per pos for 16 MFMA (was 16,
// 1:1) -> halves the LDS-read bandwidth that bounds this kernel (R9/R10
// arithmetic: 8 waves x 16 reads x ~12cyc = 1536 LDS-cyc vs 256 MFMA-cyc
// per SIMD per pos).  No Wl buffer, no per-pos barriers.
// Phase 1 (all blocks): ext rows rg*4+w -> OutE.
// Phase 2 (rg<16): one top row tr=rg -> OutT (wave 0; reloads 24 frags).
// MODE 1: D[m=x][n=co] -> [b][OH][320][64];  MODE 2: D[m=co][n=x].
// ---------------------------------------------------------------------------
template<int MODE>
__global__ __launch_bounds__(256, 2) void conv_kernel(
    const _Float16* __restrict__ Xt, const _Float16* __restrict__ Wfl,
    _Float16* __restrict__ OutE, _Float16* __restrict__ OutT, ShiftInfo si)
{
    __shared__ __align__(16) _Float16 Xs[6 * 66 * 64];
    const int xt = blockIdx.x, rg = blockIdx.y, b = blockIdx.z;
    const int x0 = xt * 64;
    const int t  = threadIdx.x;
    const int wv = t >> 6, l = t & 63;
    const int i31 = l & 31, h = l >> 5;

    int grow[6];
#pragma unroll
    for (int r = 0; r < 6; ++r) grow[r] = rg * 4 + r;   // grow[4],grow[5] may be 96,97 at rg=23

    // interior: 48 chunks (6 rows x 8 chunks of 8 x-groups), 12 per wave.
    // Pre-swizzled global source: lane l loads logical c8=(l&7)^(x&7) so the
    // LINEAR LDS write lands data where the swizzled reader expects it.
    {
#pragma unroll
        for (int j = 0; j < 12; ++j) {
            int k = wv + 4 * j;         // 0..47
            int r = k >> 3, c = k & 7;
            if ((unsigned)grow[r] < HH) {
                int x  = 1 + 8 * c + (l >> 3);       // 1..64 (always in-image)
                int c8 = (l & 7) ^ (x & 7);
                const _Float16* g =
                    &Xt[((size_t)(b * HH + grow[r]) * WW + (x0 - 1 + x)) * 64 + c8 * 8];
                gl_lds16(g, &Xs[(r * 66 + 1 + 8 * c) * 64]);
            }
        }
    }

    // zero-fill rows that are out of image (only rg==23: rows 4,5)
#pragma unroll
    for (int r = 0; r < 6; ++r) {
        if ((unsigned)grow[r] >= HH) {
            for (int u = t; u < 66 * 8; u += 256) {
                float4 zz = make_float4(0.f, 0.f, 0.f, 0.f);
                *(float4*)&Xs[r * (66 * 64) + u * 8] = zz;
            }
        }
    }

    // halo x=0 and x=65 (bounds-checked scalar path, 96 threads)
    if (t < 96) {
        int r  = t >> 4, hx = (t >> 3) & 1, c8 = t & 7;
        int x  = hx ? 65 : 0;
        int gx = x0 - 1 + x;
        float4 v = make_float4(0.f, 0.f, 0.f, 0.f);
        if ((unsigned)grow[r] < HH && (unsigned)gx < WW)
            v = *(const float4*)&Xt[((size_t)(b * HH + grow[r]) * WW + gx) * 64 + c8 * 8];
        *(float4*)&Xs[(r * 66 + x) * 64 + ((c8 ^ (x & 7)) * 8)] = v;
    }

    // phase-0 weight fragments (issued before the barrier: latency overlaps
    // the staging drain; __syncthreads' vmcnt(0) completes them)
    const _Float16* wp0 = Wfl + i31 * 16 + h * 8;
    __syncthreads();

    int xsw[3], xbase[3];
#pragma unroll
    for (int kx = 0; kx < 3; ++kx) {
        int x = i31 + kx;
        xsw[kx]   = x & 7;
        xbase[kx] = x * 64;
    }
    const int rowb = wv * (66 * 64);

    floatx16 acc[2][2];
#pragma unroll
    for (int a = 0; a < 2; ++a)
#pragma unroll
        for (int c = 0; c < 2; ++c)
            acc[a][c] = (floatx16){0.f,0.f,0.f,0.f, 0.f,0.f,0.f,0.f,
                                   0.f,0.f,0.f,0.f, 0.f,0.f,0.f,0.f};

#pragma unroll
    for (int ky = 0; ky < 3; ++ky) {
        // load this ky-row's 24 weight fragments into registers (global/L2)
        half8_t w0[12], w1[12];
#pragma unroll
        for (int kx = 0; kx < 3; ++kx)
#pragma unroll
            for (int ks = 0; ks < 4; ++ks) {
                const _Float16* wp = wp0 + (ky * 3 + kx) * 4096 + ks * 512;
                w0[kx * 4 + ks] = *(const half8_t*)(wp);
                w1[kx * 4 + ks] = *(const half8_t*)(wp + 2048);
            }
#pragma unroll
        for (int kx = 0; kx < 3; ++kx) {
#pragma unroll
            for (int ks = 0; ks < 4; ++ks) {
                const int c8  = ks * 2 + h;
                const int off = rowb + ky * (66 * 64) + xbase[kx] + ((c8 ^ xsw[kx]) * 8);
                half8_t fx0 = *(const half8_t*)(Xs + off);
                half8_t fx1 = *(const half8_t*)(Xs + off + 32 * 64);
                half8_t fw0 = w0[kx * 4 + ks], fw1 = w1[kx * 4 + ks];
                if (MODE == 1) {
                    acc[0][0] = __builtin_amdgcn_mfma_f32_32x32x16_f16(fx0, fw0, acc[0][0], 0, 0, 0);
                    acc[0][1] = __builtin_amdgcn_mfma_f32_32x32x16_f16(fx0, fw1, acc[0][1], 0, 0, 0);
                    acc[1][0] = __builtin_amdgcn_mfma_f32_32x32x16_f16(fx1, fw0, acc[1][0], 0, 0, 0);
                    acc[1][1] = __builtin_amdgcn_mfma_f32_32x32x16_f16(fx1, fw1, acc[1][1], 0, 0, 0);
                } else {
                    acc[0][0] = __builtin_amdgcn_mfma_f32_32x32x16_f16(fw0, fx0, acc[0][0], 0, 0, 0);
                    acc[0][1] = __builtin_amdgcn_mfma_f32_32x32x16_f16(fw0, fx1, acc[0][1], 0, 0, 0);
                    acc[1][0] = __builtin_amdgcn_mfma_f32_32x32x16_f16(fw1, fx0, acc[1][0], 0, 0, 0);
                    acc[1][1] = __builtin_amdgcn_mfma_f32_32x32x16_f16(fw1, fx1, acc[1][1], 0, 0, 0);
                }
            }
        }
    }

    // phase-1 epilogue: ext rows -> OutE
    {
        const int om = rg * 4 + wv;
#pragma unroll
        for (int a = 0; a < 2; ++a)
#pragma unroll
            for (int c = 0; c < 2; ++c)
#pragma unroll
                for (int r = 0; r < 16; ++r) {
                    int dm = (r & 3) + 8 * (r >> 2) + 4 * h;
                    if (MODE == 1) {
                        int x  = x0 + a * 32 + dm;
                        int co = c * 32 + i31;
                        OutE[((size_t)(b * HH + om) * WW + x) * 64 + co] = (_Float16)acc[a][c][r];
                    } else {
                        int co = a * 32 + dm;
                        int x  = x0 + c * 32 + i31;
                        OutE[((size_t)(b * 64 + co) * HH + om) * WW + x] = (_Float16)acc[a][c][r];
                    }
                }
    }

    // ---------------- phase 2: one top row for rg<16 ----------------
    if (rg < 16) {
        const int tr = rg;
        const int trow = si.rows[tr];            // always in [0,95]
        __syncthreads();                         // all waves done reading Xs

        // wave 0 preloads the 24 weight fragments for pos 0..2 (L2-resident)
        half8_t fwp0[12], fwp1[12];
        if (wv == 0) {
#pragma unroll
            for (int p = 0; p < 3; ++p)
#pragma unroll
                for (int ks = 0; ks < 4; ++ks) {
                    const _Float16* wp = Wfl + p * 4096 + ks * 512 + i31 * 16 + h * 8;
                    fwp0[p * 4 + ks] = *(const half8_t*)(wp);
                    fwp1[p * 4 + ks] = *(const half8_t*)(wp + 2048);
                }
        }

        // stage row trow into Xs row 0: interior 8 chunks (2 per wave)
#pragma unroll
        for (int j = 0; j < 2; ++j) {
            int c = wv * 2 + j;                  // 0..7
            int x = 1 + 8 * c + (l >> 3);
            int c8 = (l & 7) ^ (x & 7);
            gl_lds16(&Xt[((size_t)(b * HH + trow) * WW + (x0 - 1 + x)) * 64 + c8 * 8],
                     &Xs[(1 + 8 * c) * 64]);
        }
        // halo x=0 / x=65
        if (t < 16) {
            int hx = t >> 3, c8 = t & 7;
            int x  = hx ? 65 : 0;
            int gx = x0 - 1 + x;
            float4 v = make_float4(0.f, 0.f, 0.f, 0.f);
            if ((unsigned)gx < WW)
                v = *(const float4*)&Xt[((size_t)(b * HH + trow) * WW + gx) * 64 + c8 * 8];
            *(float4*)&Xs[x * 64 + ((c8 ^ (x & 7)) * 8)] = v;
        }
        __syncthreads();                         // staging drained

        if (wv == 0) {
            floatx16 a2[2][2];
#pragma unroll
            for (int a = 0; a < 2; ++a)
#pragma unroll
                for (int c = 0; c < 2; ++c)
                    a2[a][c] = (floatx16){0.f,0.f,0.f,0.f, 0.f,0.f,0.f,0.f,
                                          0.f,0.f,0.f,0.f, 0.f,0.f,0.f,0.f};
#pragma unroll
            for (int p = 0; p < 3; ++p) {
                const int kx = p;
                const int x = i31 + kx;
#pragma unroll
                for (int ks = 0; ks < 4; ++ks) {
                    const int c8  = ks * 2 + h;
                    const int off = x * 64 + ((c8 ^ (x & 7)) * 8);
                    half8_t fx0v = *(const half8_t*)(Xs + off);
                    half8_t fx1v = *(const half8_t*)(Xs + off + 32 * 64);
                    half8_t fw0 = fwp0[p * 4 + ks], fw1 = fwp1[p * 4 + ks];
                    if (MODE == 1) {
                        a2[0][0] = __builtin_amdgcn_mfma_f32_32x32x16_f16(fx0v, fw0, a2[0][0], 0, 0, 0);
                        a2[0][1] = __builtin_amdgcn_mfma_f32_32x32x16_f16(fx0v, fw1, a2[0][1], 0, 0, 0);
                        a2[1][0] = __builtin_amdgcn_mfma_f32_32x32x16_f16(fx1v, fw0, a2[1][0], 0, 0, 0);
                        a2[1][1] = __builtin_amdgcn_mfma_f32_32x32x16_f16(fx1v, fw1, a2[1][1], 0, 0, 0);
                    } else {
                        a2[0][0] = __builtin_amdgcn_mfma_f32_32x32x16_f16(fw0, fx0v, a2[0][0], 0, 0, 0);
                        a2[0][1] = __builtin_amdgcn_mfma_f32_32x32x16_f16(fw0, fx1v, a2[0][1], 0, 0, 0);
                        a2[1][0] = __builtin_amdgcn_mfma_f32_32x32x16_f16(fw1, fx0v, a2[1][0], 0, 0, 0);
                        a2[1][1] = __builtin_amdgcn_mfma_f32_32x32x16_f16(fw1, fx1v, a2[1][1], 0, 0, 0);
                    }
                }
            }
#pragma unroll
            for (int a = 0; a < 2; ++a)
#pragma unroll
                for (int c = 0; c < 2; ++c)
#pragma unroll
                    for (int r = 0; r < 16; ++r) {
                        int dm = (r & 3) + 8 * (r >> 2) + 4 * h;
                        if (MODE == 1) {
                            int x  = x0 + a * 32 + dm;
                            int co = c * 32 + i31;
                            OutT[((size_t)(b * 16 + tr) * WW + x) * 64 + co] = (_Float16)a2[a][c][r];
                        } else {
                            int co = a * 32 + dm;
                            int x  = x0 + c * 32 + i31;
                            OutT[((size_t)(b * 64 + co) * 16 + tr) * WW + x] = (_Float16)a2[a][c][r];
                        }
                    }
        }
    }
}

// ---------------------------------------------------------------------------
// blend1: C[b][96][320][64] + T[b][16][320][64] -> Xt2[b][96][320][64] (f16)
// x-tile = 1 column: grid (320 xt, 4 b), block 256 = 8 co8 x 32 yt.
// ---------------------------------------------------------------------------
__global__ __launch_bounds__(256) void blend1_kernel(
    const _Float16* __restrict__ Cb, const _Float16* __restrict__ T,
    const float* __restrict__ bias, _Float16* __restrict__ Xt2, ShiftInfo si)
{
    __shared__ __align__(16) _Float16 Cs[96 * 64];   // [row][co] 12.3 KB
    __shared__ __align__(16) _Float16 Ts[16 * 64];   // 2 KB
    const int x0 = blockIdx.x, b = blockIdx.y, t = threadIdx.x;
    const half8_t z = {0,0,0,0,0,0,0,0};

    {
        const int w = t >> 6, l = t & 63;
        const int c8 = l & 7;
#pragma unroll
        for (int j = 0; j < 3; ++j) {
            int k = w + 4 * j;                   // 0..11, 8 rows each
            int row = 8 * k + (l >> 3);
            gl_lds16(&Cb[((size_t)(b * HH + row) * WW + x0) * 64 + c8 * 8],
                     &Cs[k * 512]);
        }
        if (w < 2) {
            int row = 8 * w + (l >> 3);
            gl_lds16(&T[((size_t)(b * 16 + row) * WW + x0) * 64 + c8 * 8],
                     &Ts[w * 512]);
        }
    }
    __syncthreads();

    const int co8 = t & 7, yt = t >> 3;
    half8_t bv;
#pragma unroll
    for (int j = 0; j < 8; ++j) bv[j] = (_Float16)bias[co8 * 8 + j];

    const int y0 = yt * 3;
    half8_t cur[NP];
#pragma unroll
    for (int d = 0; d < NP; ++d) {
        int r = y0 + si.s0[d] - 1;
        cur[d] = (r < HH) ? *(const half8_t*)&Cs[r * 64 + co8 * 8] : z;
    }
    for (int y = y0; y < y0 + 3; ++y) {
        half8_t m = z;
#pragma unroll
        for (int d = 0; d < NP; ++d) {
            int r1 = y + si.s0[d];
            half8_t v1 = (r1 < HH) ? *(const half8_t*)&Cs[r1 * 64 + co8 * 8] : z;
            half8_t v0 = cur[d];
            cur[d] = v1;
            _Float16 a = (_Float16)si.wa[d], wg = (_Float16)si.wb[d];
            half8_t p;
            if (y == 0) {
                half8_t t0 = *(const half8_t*)&Ts[(2 * d) * 64 + co8 * 8];
                half8_t t1 = *(const half8_t*)&Ts[(2 * d + 1) * 64 + co8 * 8];
                p = a * (v0 - t0) + wg * (v1 - t1);
            } else {
                p = a * v0 + wg * v1;
            }
            m = (d == 0) ? p : __builtin_elementwise_max(m, p);
        }
        half8_t o = __builtin_elementwise_max(m + bv, z);
        *(half8_t*)&Xt2[((size_t)(b * HH + y) * WW + x0) * 64 + co8 * 8] = o;
    }
}

// ---------------------------------------------------------------------------
// blend2: C[b][64][96][320] + T[b][64][16][320] -> Out fp32 [b][64][96][320]
// grid 1280 = (xt 5) x (co 64) x (b 4), block 256.
// ---------------------------------------------------------------------------
__global__ __launch_bounds__(256) void blend2_kernel(
    const _Float16* __restrict__ Cb, const _Float16* __restrict__ T,
    const float* __restrict__ bias, float* __restrict__ Out, ShiftInfo si)
{
    __shared__ __align__(16) _Float16 Cs[96 * 64];
    __shared__ __align__(16) _Float16 Ts[16 * 64];
    const int task = blockIdx.x, t = threadIdx.x;
    const int xt = task % 5;
    const int rem = task / 5;
    const int co = rem & 63;
    const int b  = rem >> 6;
    const int x0 = xt * 64;
    const half8_t z = {0,0,0,0,0,0,0,0};

    {
        const int w = t >> 6, l = t & 63;
        const int x8 = l & 7;
#pragma unroll
        for (int j = 0; j < 3; ++j) {
            int k = w + 4 * j;                   // 0..11, 8 rows each
            int row = 8 * k + (l >> 3);
            gl_lds16(&Cb[((size_t)(b * 64 + co) * HH + row) * WW + x0 + x8 * 8],
                     &Cs[k * 512]);
        }
        if (w < 2) {
            int row = 8 * w + (l >> 3);
            gl_lds16(&T[((size_t)(b * 64 + co) * 16 + row) * WW + x0 + x8 * 8],
                     &Ts[w * 512]);
        }
    }
    __syncthreads();

    const int x8 = t & 7, yt = t >> 3;
    const float bvf = bias[co];
    const int y0 = yt * 3;

    half8_t cur[NP];
#pragma unroll
    for (int d = 0; d < NP; ++d) {
        int r = y0 + si.s0[d] - 1;
        cur[d] = (r < HH) ? *(const half8_t*)&Cs[r * 64 + x8 * 8] : z;
    }
    for (int y = y0; y < y0 + 3; ++y) {
        half8_t m = z;
#pragma unroll
        for (int d = 0; d < NP; ++d) {
            int r1 = y + si.s0[d];
            half8_t v1 = (r1 < HH) ? *(const half8_t*)&Cs[r1 * 64 + x8 * 8] : z;
            half8_t v0 = cur[d];
            cur[d] = v1;
            _Float16 a = (_Float16)si.wa[d], wg = (_Float16)si.wb[d];
            half8_t p;
            if (y == 0) {
                half8_t t0 = *(const half8_t*)&Ts[(2 * d) * 64 + x8 * 8];
                half8_t t1 = *(const half8_t*)&Ts[(2 * d + 1) * 64 + x8 * 8];
                p = a * (v0 - t0) + wg * (v1 - t1);
            } else {
                p = a * v0 + wg * v1;
            }
            m = (d == 0) ? p : __builtin_elementwise_max(m, p);
        }
        float4 o0, o1;
        o0.x = fmaxf((float)m[0] + bvf, 0.f);
        o0.y = fmaxf((float)m[1] + bvf, 0.f);
        o0.z = fmaxf((float)m[2] + bvf, 0.f);
        o0.w = fmaxf((float)m[3] + bvf, 0.f);
        o1.x = fmaxf((float)m[4] + bvf, 0.f);
        o1.y = fmaxf((float)m[5] + bvf, 0.f);
        o1.z = fmaxf((float)m[6] + bvf, 0.f);
        o1.w = fmaxf((float)m[7] + bvf, 0.f);
        float* op = Out + ((size_t)(b * 64 + co) * HH + y) * WW + x0 + x8 * 8;
        *(float4*)op = o0;
        *(float4*)(op + 4) = o1;
    }
}

// ---------------------------------------------------------------------------
extern "C" void kernel_launch(void* const* d_in, const int* in_sizes, int n_in,
                              void* d_out, int out_size, void* d_ws, size_t ws_size,
                              hipStream_t stream) {
    const float* x  = (const float*)d_in[0];
    const float* W1 = (const float*)d_in[1];
    const float* b1 = (const float*)d_in[2];
    const float* W2 = (const float*)d_in[3];
    const float* b2 = (const float*)d_in[4];
    float* out = (float*)d_out;

    _Float16* Xt1 = (_Float16*)d_ws;            // 7,864,320 halves
    _Float16* Cb  = Xt1 + 7864320;              // 7,864,320
    _Float16* T   = Cb  + 7864320;              // 1,310,720
    _Float16* Wf  = T   + 1310720;              // 73,728 (both layers, MFMA layout)
    _Float16* Xt2 = (_Float16*)d_out;           // f16 scratch inside d_out

    ShiftInfo si;
    for (int d = 0; d < NP; ++d) {
        double disp = 0.02 + d * (0.98 / 7.0);
        double sh   = 76.0 * disp;
        int s0      = (int)floor(sh);
        double w    = sh - (double)s0;
        si.s0[d] = s0;
        si.wa[d] = (float)(1.0 - w);
        si.wb[d] = (float)w;
        si.rows[2 * d]     = s0 - 1;
        si.rows[2 * d + 1] = s0;
    }

    prep_kernel<<<dim3(786), 256, 0, stream>>>(x, W1, W2, Xt1, Wf);

    conv_kernel<1><<<dim3(5, 24, 4), 256, 0, stream>>>(Xt1, Wf, Cb, T, si);
    blend1_kernel<<<dim3(320, 4), 256, 0, stream>>>(Cb, T, b1, Xt2, si);

    conv_kernel<2><<<dim3(5, 24, 4), 256, 0, stream>>>(Xt2, Wf + 36864, Cb, T, si);
    blend2_kernel<<<dim3(1280), 256, 0, stream>>>(Cb, T, b2, out, si);
}

// Round 12
// 75.084 us; speedup vs baseline: 1.0789x; 1.0789x over previous
//
#include <hip/hip_runtime.h>
#include <math.h>

#define HH 96
#define WW 320
#define NP 8

typedef _Float16 half8_t  __attribute__((ext_vector_type(8)));
typedef _Float16 half4_t  __attribute__((ext_vector_type(4)));
typedef float    floatx16 __attribute__((ext_vector_type(16)));

struct ShiftInfo {
    int   s0[NP];
    float wa[NP];
    float wb[NP];
    int   rows[16];
};

// async global->LDS, 16B per lane, dest = wave-uniform base + lane*16
__device__ __forceinline__ void gl_lds16(const _Float16* g, _Float16* l) {
    __builtin_amdgcn_global_load_lds(
        (const __attribute__((address_space(1))) void*)g,
        (__attribute__((address_space(3))) void*)l, 16, 0, 0);
}

// blend LDS tile: element (row, chunk c) lives at row*64 + (c ^ (row&7))*8.
// Staged via linear global_load_lds with pre-swizzled SOURCE chunk
// (c8s = (l&7) ^ (row&7)); breaks the stride-128B 8-way bank conflict
// (bank was x8*4 for all rows; y steps by 3 per yt, gcd(3,8)=1 -> the 8
// rows per wave hit 8 distinct banks after the XOR).
#define CSW(row, c) (((row) * 64) + ((((c) ^ ((row) & 7))) * 8))

// ---------------------------------------------------------------------------
// prep: blockIdx.x < 768 -> transpose+cvt one (b,y,x-half) strip of X into Xt
//       blockIdx.x >= 768 -> weight cvt to MFMA-fragment-native layout.
// ---------------------------------------------------------------------------
__global__ __launch_bounds__(256) void prep_kernel(
    const float* __restrict__ X, const float* __restrict__ W1,
    const float* __restrict__ W2, _Float16* __restrict__ Xt,
    _Float16* __restrict__ Wf)
{
    __shared__ __align__(16) _Float16 Ls[64 * 163];
    const int bx = blockIdx.x, t = threadIdx.x;
    if (bx < 768) {
        const int r = bx >> 1, xh = bx & 1;
        const int y = r % HH, b = r / HH;
        const int xbase = xh * 160;
        for (int u = t; u < 64 * 40; u += 256) {
            int ci = u / 40;
            int xi = (u - ci * 40) * 4;
            float4 v = *(const float4*)&X[((size_t)(b * 64 + ci) * HH + y) * WW + xbase + xi];
            half4_t hv = { (_Float16)v.x, (_Float16)v.y, (_Float16)v.z, (_Float16)v.w };
            *(half4_t*)&Ls[ci * 163 + xi] = hv;
        }
        __syncthreads();
        const int ci8 = t & 7, xg = t >> 3;
        for (int it = 0; it < 5; ++it) {
            int x = xg + 32 * it;
            half8_t o;
#pragma unroll
            for (int j = 0; j < 8; ++j) o[j] = Ls[(ci8 * 8 + j) * 163 + x];
            *(half8_t*)&Xt[((size_t)(b * HH + y) * WW + xbase + x) * 64 + ci8 * 8] = o;
        }
    } else {
        const int k = bx - 768;                  // 0..17
        const int layer = k / 9, pos = k - layer * 9;
        const float* Ws = layer ? W2 : W1;
        _Float16* Wd = Wf + layer * 36864 + pos * 4096;
        for (int u = t; u < 4096; u += 256) {
            int mt  = u >> 11;
            int ks  = (u >> 9) & 3;
            int i31 = (u >> 4) & 31;
            int h   = (u >> 3) & 1;
            int j   = u & 7;
            int co  = mt * 32 + i31;
            int ci  = ks * 16 + h * 8 + j;
            Wd[u] = (_Float16)Ws[((size_t)co * 64 + ci) * 9 + pos];
        }
    }
}

// ---------------------------------------------------------------------------
// conv core (ext rows), LDS-staged weights double-buffered per pos (R9/R10).
// s_setprio(1) wraps the MFMA cluster (T5): this schedule is phase-split
// (stage || ds_read || MFMA with per-pos barriers), the regime where wave
// priority arbitration pays.
// X fragments from the XOR-swizzled Xs tile:
//   elem(row, x, c8) at (row*66+x)*64 + (c8 ^ (x&7))*8   (halves)
// ---------------------------------------------------------------------------
template<int MODE>
__device__ __forceinline__ void conv_core(
    const _Float16* __restrict__ Xs, _Float16* __restrict__ Wl,
    const _Float16* __restrict__ Wg, int w, int i31, int h, int t,
    floatx16 (&acc)[2][2])
{
    int xsw[3], xbase[3];
#pragma unroll
    for (int kx = 0; kx < 3; ++kx) {
        int x = i31 + kx;
        xsw[kx]   = x & 7;
        xbase[kx] = x * 64;
    }
    const int rowb  = w * (66 * 64);
    const int wv    = t >> 6, l = t & 63;
    const int wfrag = i31 * 16 + h * 8;

#pragma unroll
    for (int p = 0; p < 9; ++p) {
        // stage pos p+1 into the other buffer (2 x 1KB chunks per wave)
        if (p + 1 < 9) {
#pragma unroll
            for (int j = 0; j < 2; ++j) {
                int ch = wv * 2 + j;
                gl_lds16(Wg + (p + 1) * 4096 + ch * 512 + l * 8,
                         Wl + ((p + 1) & 1) * 4096 + ch * 512);
            }
        }
        const int ky = p / 3, kx = p - ky * 3;
        const _Float16* wb = Wl + (p & 1) * 4096 + wfrag;
        half8_t fw0[4], fw1[4], fx0[4], fx1[4];
#pragma unroll
        for (int ks = 0; ks < 4; ++ks) {
            fw0[ks] = *(const half8_t*)(wb + ks * 512);
            fw1[ks] = *(const half8_t*)(wb + ks * 512 + 2048);
            const int c8  = ks * 2 + h;
            const int off = rowb + ky * (66 * 64) + xbase[kx] + ((c8 ^ xsw[kx]) * 8);
            fx0[ks] = *(const half8_t*)(Xs + off);
            fx1[ks] = *(const half8_t*)(Xs + off + 32 * 64);
        }
        __builtin_amdgcn_s_setprio(1);
#pragma unroll
        for (int ks = 0; ks < 4; ++ks) {
            if (MODE == 1) {
                acc[0][0] = __builtin_amdgcn_mfma_f32_32x32x16_f16(fx0[ks], fw0[ks], acc[0][0], 0, 0, 0);
                acc[0][1] = __builtin_amdgcn_mfma_f32_32x32x16_f16(fx0[ks], fw1[ks], acc[0][1], 0, 0, 0);
                acc[1][0] = __builtin_amdgcn_mfma_f32_32x32x16_f16(fx1[ks], fw0[ks], acc[1][0], 0, 0, 0);
                acc[1][1] = __builtin_amdgcn_mfma_f32_32x32x16_f16(fx1[ks], fw1[ks], acc[1][1], 0, 0, 0);
            } else {
                acc[0][0] = __builtin_amdgcn_mfma_f32_32x32x16_f16(fw0[ks], fx0[ks], acc[0][0], 0, 0, 0);
                acc[0][1] = __builtin_amdgcn_mfma_f32_32x32x16_f16(fw0[ks], fx1[ks], acc[0][1], 0, 0, 0);
                acc[1][0] = __builtin_amdgcn_mfma_f32_32x32x16_f16(fw1[ks], fx0[ks], acc[1][0], 0, 0, 0);
                acc[1][1] = __builtin_amdgcn_mfma_f32_32x32x16_f16(fw1[ks], fx1[ks], acc[1][1], 0, 0, 0);
            }
        }
        __builtin_amdgcn_s_setprio(0);
        if (p + 1 < 9) __syncthreads();
    }
}

// ---------------------------------------------------------------------------
// MFMA implicit-GEMM conv, merged grid: (5, 24, 4) = 480 blocks <= 512
// capacity (2 blocks/CU @ 67 KB LDS) -> single dispatch wave.
// Phase 1 (all blocks): ext rows rg*4+w -> OutE.
// Phase 2 (rg<16): one top row tr=rg -> OutT (wave 0, weights preloaded).
// MODE 1: D[m=x][n=co] -> [b][OH][320][64];  MODE 2: D[m=co][n=x].
// ---------------------------------------------------------------------------
template<int MODE>
__global__ __launch_bounds__(256, 2) void conv_kernel(
    const _Float16* __restrict__ Xt, const _Float16* __restrict__ Wfl,
    _Float16* __restrict__ OutE, _Float16* __restrict__ OutT, ShiftInfo si)
{
    __shared__ __align__(16) _Float16 Xs[6 * 66 * 64];
    __shared__ __align__(16) _Float16 Wl[2 * 4096];
    const int xt = blockIdx.x, rg = blockIdx.y, b = blockIdx.z;
    const int x0 = xt * 64;
    const int t  = threadIdx.x;
    const int wv = t >> 6, l = t & 63;
    const int i31 = l & 31, h = l >> 5;

    int grow[6];
#pragma unroll
    for (int r = 0; r < 6; ++r) grow[r] = rg * 4 + r;   // grow[4],grow[5] may be 96,97 at rg=23

    // weight pos0 stage (on pos0's critical path; issue first)
    {
#pragma unroll
        for (int j = 0; j < 2; ++j) {
            int ch = wv * 2 + j;
            gl_lds16(Wfl + ch * 512 + l * 8, Wl + ch * 512);
        }
    }

    // interior: 48 chunks (6 rows x 8 chunks of 8 x-groups), 12 per wave.
    // Pre-swizzled global source: lane l loads logical c8=(l&7)^(x&7) so the
    // LINEAR LDS write lands data where the swizzled reader expects it.
    {
#pragma unroll
        for (int j = 0; j < 12; ++j) {
            int k = wv + 4 * j;         // 0..47
            int r = k >> 3, c = k & 7;
            if ((unsigned)grow[r] < HH) {
                int x  = 1 + 8 * c + (l >> 3);       // 1..64 (always in-image)
                int c8 = (l & 7) ^ (x & 7);
                const _Float16* g =
                    &Xt[((size_t)(b * HH + grow[r]) * WW + (x0 - 1 + x)) * 64 + c8 * 8];
                gl_lds16(g, &Xs[(r * 66 + 1 + 8 * c) * 64]);
            }
        }
    }

    // zero-fill rows that are out of image (only rg==23: rows 4,5)
#pragma unroll
    for (int r = 0; r < 6; ++r) {
        if ((unsigned)grow[r] >= HH) {
            for (int u = t; u < 66 * 8; u += 256) {
                float4 zz = make_float4(0.f, 0.f, 0.f, 0.f);
                *(float4*)&Xs[r * (66 * 64) + u * 8] = zz;
            }
        }
    }

    // halo x=0 and x=65 (bounds-checked scalar path, 96 threads)
    if (t < 96) {
        int r  = t >> 4, hx = (t >> 3) & 1, c8 = t & 7;
        int x  = hx ? 65 : 0;
        int gx = x0 - 1 + x;
        float4 v = make_float4(0.f, 0.f, 0.f, 0.f);
        if ((unsigned)grow[r] < HH && (unsigned)gx < WW)
            v = *(const float4*)&Xt[((size_t)(b * HH + grow[r]) * WW + gx) * 64 + c8 * 8];
        *(float4*)&Xs[(r * 66 + x) * 64 + ((c8 ^ (x & 7)) * 8)] = v;
    }
    __syncthreads();

    floatx16 acc[2][2];
#pragma unroll
    for (int a = 0; a < 2; ++a)
#pragma unroll
        for (int c = 0; c < 2; ++c)
            acc[a][c] = (floatx16){0.f,0.f,0.f,0.f, 0.f,0.f,0.f,0.f,
                                   0.f,0.f,0.f,0.f, 0.f,0.f,0.f,0.f};

    conv_core<MODE>(Xs, Wl, Wfl, wv, i31, h, t, acc);

    // phase-1 epilogue: ext rows -> OutE
    {
        const int om = rg * 4 + wv;
#pragma unroll
        for (int a = 0; a < 2; ++a)
#pragma unroll
            for (int c = 0; c < 2; ++c)
#pragma unroll
                for (int r = 0; r < 16; ++r) {
                    int dm = (r & 3) + 8 * (r >> 2) + 4 * h;
                    if (MODE == 1) {
                        int x  = x0 + a * 32 + dm;
                        int co = c * 32 + i31;
                        OutE[((size_t)(b * HH + om) * WW + x) * 64 + co] = (_Float16)acc[a][c][r];
                    } else {
                        int co = a * 32 + dm;
                        int x  = x0 + c * 32 + i31;
                        OutE[((size_t)(b * 64 + co) * HH + om) * WW + x] = (_Float16)acc[a][c][r];
                    }
                }
    }

    // ---------------- phase 2: one top row for rg<16 ----------------
    if (rg < 16) {
        const int tr = rg;
        const int trow = si.rows[tr];            // always in [0,95]
        __syncthreads();                         // all waves done reading Xs

        // wave 0 preloads the 24 weight fragments for pos 0..2 (L2-resident)
        half8_t fwp0[12], fwp1[12];
        if (wv == 0) {
#pragma unroll
            for (int p = 0; p < 3; ++p)
#pragma unroll
                for (int ks = 0; ks < 4; ++ks) {
                    const _Float16* wp = Wfl + p * 4096 + ks * 512 + i31 * 16 + h * 8;
                    fwp0[p * 4 + ks] = *(const half8_t*)(wp);
                    fwp1[p * 4 + ks] = *(const half8_t*)(wp + 2048);
                }
        }

        // stage row trow into Xs row 0: interior 8 chunks (2 per wave)
#pragma unroll
        for (int j = 0; j < 2; ++j) {
            int c = wv * 2 + j;                  // 0..7
            int x = 1 + 8 * c + (l >> 3);
            int c8 = (l & 7) ^ (x & 7);
            gl_lds16(&Xt[((size_t)(b * HH + trow) * WW + (x0 - 1 + x)) * 64 + c8 * 8],
                     &Xs[(1 + 8 * c) * 64]);
        }
        // halo x=0 / x=65
        if (t < 16) {
            int hx = t >> 3, c8 = t & 7;
            int x  = hx ? 65 : 0;
            int gx = x0 - 1 + x;
            float4 v = make_float4(0.f, 0.f, 0.f, 0.f);
            if ((unsigned)gx < WW)
                v = *(const float4*)&Xt[((size_t)(b * HH + trow) * WW + gx) * 64 + c8 * 8];
            *(float4*)&Xs[x * 64 + ((c8 ^ (x & 7)) * 8)] = v;
        }
        __syncthreads();                         // staging drained

        if (wv == 0) {
            floatx16 a2[2][2];
#pragma unroll
            for (int a = 0; a < 2; ++a)
#pragma unroll
                for (int c = 0; c < 2; ++c)
                    a2[a][c] = (floatx16){0.f,0.f,0.f,0.f, 0.f,0.f,0.f,0.f,
                                          0.f,0.f,0.f,0.f, 0.f,0.f,0.f,0.f};
#pragma unroll
            for (int p = 0; p < 3; ++p) {
                const int kx = p;
                const int x = i31 + kx;
#pragma unroll
                for (int ks = 0; ks < 4; ++ks) {
                    const int c8  = ks * 2 + h;
                    const int off = x * 64 + ((c8 ^ (x & 7)) * 8);
                    half8_t fx0v = *(const half8_t*)(Xs + off);
                    half8_t fx1v = *(const half8_t*)(Xs + off + 32 * 64);
                    half8_t w0 = fwp0[p * 4 + ks], w1 = fwp1[p * 4 + ks];
                    if (MODE == 1) {
                        a2[0][0] = __builtin_amdgcn_mfma_f32_32x32x16_f16(fx0v, w0, a2[0][0], 0, 0, 0);
                        a2[0][1] = __builtin_amdgcn_mfma_f32_32x32x16_f16(fx0v, w1, a2[0][1], 0, 0, 0);
                        a2[1][0] = __builtin_amdgcn_mfma_f32_32x32x16_f16(fx1v, w0, a2[1][0], 0, 0, 0);
                        a2[1][1] = __builtin_amdgcn_mfma_f32_32x32x16_f16(fx1v, w1, a2[1][1], 0, 0, 0);
                    } else {
                        a2[0][0] = __builtin_amdgcn_mfma_f32_32x32x16_f16(w0, fx0v, a2[0][0], 0, 0, 0);
                        a2[0][1] = __builtin_amdgcn_mfma_f32_32x32x16_f16(w0, fx1v, a2[0][1], 0, 0, 0);
                        a2[1][0] = __builtin_amdgcn_mfma_f32_32x32x16_f16(w1, fx0v, a2[1][0], 0, 0, 0);
                        a2[1][1] = __builtin_amdgcn_mfma_f32_32x32x16_f16(w1, fx1v, a2[1][1], 0, 0, 0);
                    }
                }
            }
#pragma unroll
            for (int a = 0; a < 2; ++a)
#pragma unroll
                for (int c = 0; c < 2; ++c)
#pragma unroll
                    for (int r = 0; r < 16; ++r) {
                        int dm = (r & 3) + 8 * (r >> 2) + 4 * h;
                        if (MODE == 1) {
                            int x  = x0 + a * 32 + dm;
                            int co = c * 32 + i31;
                            OutT[((size_t)(b * 16 + tr) * WW + x) * 64 + co] = (_Float16)a2[a][c][r];
                        } else {
                            int co = a * 32 + dm;
                            int x  = x0 + c * 32 + i31;
                            OutT[((size_t)(b * 64 + co) * 16 + tr) * WW + x] = (_Float16)a2[a][c][r];
                        }
                    }
        }
    }
}

// ---------------------------------------------------------------------------
// blend1: C[b][96][320][64] + T[b][16][320][64] -> Xt2[b][96][320][64] (f16)
// x-tile = 1 column: grid (320 xt, 4 b), block 256 = 8 co8 x 32 yt.
// LDS layout bank-swizzled via CSW (conflict-free reads; was 8-way).
// ---------------------------------------------------------------------------
__global__ __launch_bounds__(256) void blend1_kernel(
    const _Float16* __restrict__ Cb, const _Float16* __restrict__ T,
    const float* __restrict__ bias, _Float16* __restrict__ Xt2, ShiftInfo si)
{
    __shared__ __align__(16) _Float16 Cs[96 * 64];   // [row][co] 12.3 KB
    __shared__ __align__(16) _Float16 Ts[16 * 64];   // 2 KB
    const int x0 = blockIdx.x, b = blockIdx.y, t = threadIdx.x;
    const half8_t z = {0,0,0,0,0,0,0,0};

    {
        const int w = t >> 6, l = t & 63;
        const int c8s = (l & 7) ^ ((l >> 3) & 7);    // = (l&7) ^ (row&7)
#pragma unroll
        for (int j = 0; j < 3; ++j) {
            int k = w + 4 * j;                   // 0..11, 8 rows each
            int row = 8 * k + (l >> 3);
            gl_lds16(&Cb[((size_t)(b * HH + row) * WW + x0) * 64 + c8s * 8],
                     &Cs[k * 512]);
        }
        if (w < 2) {
            int row = 8 * w + (l >> 3);
            gl_lds16(&T[((size_t)(b * 16 + row) * WW + x0) * 64 + c8s * 8],
                     &Ts[w * 512]);
        }
    }
    __syncthreads();

    const int co8 = t & 7, yt = t >> 3;
    half8_t bv;
#pragma unroll
    for (int j = 0; j < 8; ++j) bv[j] = (_Float16)bias[co8 * 8 + j];

    const int y0 = yt * 3;
    half8_t cur[NP];
#pragma unroll
    for (int d = 0; d < NP; ++d) {
        int r = y0 + si.s0[d] - 1;
        cur[d] = (r < HH) ? *(const half8_t*)&Cs[CSW(r, co8)] : z;
    }
    for (int y = y0; y < y0 + 3; ++y) {
        half8_t m = z;
#pragma unroll
        for (int d = 0; d < NP; ++d) {
            int r1 = y + si.s0[d];
            half8_t v1 = (r1 < HH) ? *(const half8_t*)&Cs[CSW(r1, co8)] : z;
            half8_t v0 = cur[d];
            cur[d] = v1;
            _Float16 a = (_Float16)si.wa[d], wg = (_Float16)si.wb[d];
            half8_t p;
            if (y == 0) {
                half8_t t0 = *(const half8_t*)&Ts[CSW(2 * d, co8)];
                half8_t t1 = *(const half8_t*)&Ts[CSW(2 * d + 1, co8)];
                p = a * (v0 - t0) + wg * (v1 - t1);
            } else {
                p = a * v0 + wg * v1;
            }
            m = (d == 0) ? p : __builtin_elementwise_max(m, p);
        }
        half8_t o = __builtin_elementwise_max(m + bv, z);
        *(half8_t*)&Xt2[((size_t)(b * HH + y) * WW + x0) * 64 + co8 * 8] = o;
    }
}

// ---------------------------------------------------------------------------
// blend2: C[b][64][96][320] + T[b][64][16][320] -> Out fp32 [b][64][96][320]
// grid 1280 = (xt 5) x (co 64) x (b 4), block 256.
// LDS layout bank-swizzled via CSW (conflict-free reads; was 8-way).
// ---------------------------------------------------------------------------
__global__ __launch_bounds__(256) void blend2_kernel(
    const _Float16* __restrict__ Cb, const _Float16* __restrict__ T,
    const float* __restrict__ bias, float* __restrict__ Out, ShiftInfo si)
{
    __shared__ __align__(16) _Float16 Cs[96 * 64];
    __shared__ __align__(16) _Float16 Ts[16 * 64];
    const int task = blockIdx.x, t = threadIdx.x;
    const int xt = task % 5;
    const int rem = task / 5;
    const int co = rem & 63;
    const int b  = rem >> 6;
    const int x0 = xt * 64;
    const half8_t z = {0,0,0,0,0,0,0,0};

    {
        const int w = t >> 6, l = t & 63;
        const int x8s = (l & 7) ^ ((l >> 3) & 7);    // = (l&7) ^ (row&7)
#pragma unroll
        for (int j = 0; j < 3; ++j) {
            int k = w + 4 * j;                   // 0..11, 8 rows each
            int row = 8 * k + (l >> 3);
            gl_lds16(&Cb[((size_t)(b * 64 + co) * HH + row) * WW + x0 + x8s * 8],
                     &Cs[k * 512]);
        }
        if (w < 2) {
            int row = 8 * w + (l >> 3);
            gl_lds16(&T[((size_t)(b * 64 + co) * 16 + row) * WW + x0 + x8s * 8],
                     &Ts[w * 512]);
        }
    }
    __syncthreads();

    const int x8 = t & 7, yt = t >> 3;
    const float bvf = bias[co];
    const int y0 = yt * 3;

    half8_t cur[NP];
#pragma unroll
    for (int d = 0; d < NP; ++d) {
        int r = y0 + si.s0[d] - 1;
        cur[d] = (r < HH) ? *(const half8_t*)&Cs[CSW(r, x8)] : z;
    }
    for (int y = y0; y < y0 + 3; ++y) {
        half8_t m = z;
#pragma unroll
        for (int d = 0; d < NP; ++d) {
            int r1 = y + si.s0[d];
            half8_t v1 = (r1 < HH) ? *(const half8_t*)&Cs[CSW(r1, x8)] : z;
            half8_t v0 = cur[d];
            cur[d] = v1;
            _Float16 a = (_Float16)si.wa[d], wg = (_Float16)si.wb[d];
            half8_t p;
            if (y == 0) {
                half8_t t0 = *(const half8_t*)&Ts[CSW(2 * d, x8)];
                half8_t t1 = *(const half8_t*)&Ts[CSW(2 * d + 1, x8)];
                p = a * (v0 - t0) + wg * (v1 - t1);
            } else {
                p = a * v0 + wg * v1;
            }
            m = (d == 0) ? p : __builtin_elementwise_max(m, p);
        }
        float4 o0, o1;
        o0.x = fmaxf((float)m[0] + bvf, 0.f);
        o0.y = fmaxf((float)m[1] + bvf, 0.f);
        o0.z = fmaxf((float)m[2] + bvf, 0.f);
        o0.w = fmaxf((float)m[3] + bvf, 0.f);
        o1.x = fmaxf((float)m[4] + bvf, 0.f);
        o1.y = fmaxf((float)m[5] + bvf, 0.f);
        o1.z = fmaxf((float)m[6] + bvf, 0.f);
        o1.w = fmaxf((float)m[7] + bvf, 0.f);
        float* op = Out + ((size_t)(b * 64 + co) * HH + y) * WW + x0 + x8 * 8;
        *(float4*)op = o0;
        *(float4*)(op + 4) = o1;
    }
}

// ---------------------------------------------------------------------------
extern "C" void kernel_launch(void* const* d_in, const int* in_sizes, int n_in,
                              void* d_out, int out_size, void* d_ws, size_t ws_size,
                              hipStream_t stream) {
    const float* x  = (const float*)d_in[0];
    const float* W1 = (const float*)d_in[1];
    const float* b1 = (const float*)d_in[2];
    const float* W2 = (const float*)d_in[3];
    const float* b2 = (const float*)d_in[4];
    float* out = (float*)d_out;

    _Float16* Xt1 = (_Float16*)d_ws;            // 7,864,320 halves
    _Float16* Cb  = Xt1 + 7864320;              // 7,864,320
    _Float16* T   = Cb  + 7864320;              // 1,310,720
    _Float16* Wf  = T   + 1310720;              // 73,728 (both layers, MFMA layout)
    _Float16* Xt2 = (_Float16*)d_out;           // f16 scratch inside d_out

    ShiftInfo si;
    for (int d = 0; d < NP; ++d) {
        double disp = 0.02 + d * (0.98 / 7.0);
        double sh   = 76.0 * disp;
        int s0      = (int)floor(sh);
        double w    = sh - (double)s0;
        si.s0[d] = s0;
        si.wa[d] = (float)(1.0 - w);
        si.wb[d] = (float)w;
        si.rows[2 * d]     = s0 - 1;
        si.rows[2 * d + 1] = s0;
    }

    prep_kernel<<<dim3(786), 256, 0, stream>>>(x, W1, W2, Xt1, Wf);

    conv_kernel<1><<<dim3(5, 24, 4), 256, 0, stream>>>(Xt1, Wf, Cb, T, si);
    blend1_kernel<<<dim3(320, 4), 256, 0, stream>>>(Cb, T, b1, Xt2, si);

    conv_kernel<2><<<dim3(5, 24, 4), 256, 0, stream>>>(Xt2, Wf + 36864, Cb, T, si);
    blend2_kernel<<<dim3(1280), 256, 0, stream>>>(Cb, T, b2, out, si);
}

// Round 13
// 74.697 us; speedup vs baseline: 1.0845x; 1.0052x over previous
//
#include <hip/hip_runtime.h>
#include <math.h>

#define HH 96
#define WW 320
#define NP 8

typedef _Float16 half8_t  __attribute__((ext_vector_type(8)));
typedef _Float16 half4_t  __attribute__((ext_vector_type(4)));
typedef float    floatx16 __attribute__((ext_vector_type(16)));

struct ShiftInfo {
    int   s0[NP];
    float wa[NP];
    float wb[NP];
    int   rows[16];
};

// async global->LDS, 16B per lane, dest = wave-uniform base + lane*16
__device__ __forceinline__ void gl_lds16(const _Float16* g, _Float16* l) {
    __builtin_amdgcn_global_load_lds(
        (const __attribute__((address_space(1))) void*)g,
        (__attribute__((address_space(3))) void*)l, 16, 0, 0);
}

// blend LDS tile: element (row, chunk c) lives at row*64 + (c ^ (row&7))*8.
// Staged via linear global_load_lds with pre-swizzled SOURCE chunk
// (c8s = (l&7) ^ (row&7)); breaks the stride-128B 8-way bank conflict.
#define CSW(row, c) (((row) * 64) + ((((c) ^ ((row) & 7))) * 8))

// ---------------------------------------------------------------------------
// prep: blockIdx.x < 768 -> transpose+cvt one (b,y,x-half) strip of X into Xt
//       blockIdx.x >= 768 -> weight cvt to MFMA-fragment-native layout.
// ---------------------------------------------------------------------------
__global__ __launch_bounds__(256) void prep_kernel(
    const float* __restrict__ X, const float* __restrict__ W1,
    const float* __restrict__ W2, _Float16* __restrict__ Xt,
    _Float16* __restrict__ Wf)
{
    __shared__ __align__(16) _Float16 Ls[64 * 163];
    const int bx = blockIdx.x, t = threadIdx.x;
    if (bx < 768) {
        const int r = bx >> 1, xh = bx & 1;
        const int y = r % HH, b = r / HH;
        const int xbase = xh * 160;
        for (int u = t; u < 64 * 40; u += 256) {
            int ci = u / 40;
            int xi = (u - ci * 40) * 4;
            float4 v = *(const float4*)&X[((size_t)(b * 64 + ci) * HH + y) * WW + xbase + xi];
            half4_t hv = { (_Float16)v.x, (_Float16)v.y, (_Float16)v.z, (_Float16)v.w };
            *(half4_t*)&Ls[ci * 163 + xi] = hv;
        }
        __syncthreads();
        const int ci8 = t & 7, xg = t >> 3;
        for (int it = 0; it < 5; ++it) {
            int x = xg + 32 * it;
            half8_t o;
#pragma unroll
            for (int j = 0; j < 8; ++j) o[j] = Ls[(ci8 * 8 + j) * 163 + x];
            *(half8_t*)&Xt[((size_t)(b * HH + y) * WW + xbase + x) * 64 + ci8 * 8] = o;
        }
    } else {
        const int k = bx - 768;                  // 0..17
        const int layer = k / 9, pos = k - layer * 9;
        const float* Ws = layer ? W2 : W1;
        _Float16* Wd = Wf + layer * 36864 + pos * 4096;
        for (int u = t; u < 4096; u += 256) {
            int mt  = u >> 11;
            int ks  = (u >> 9) & 3;
            int i31 = (u >> 4) & 31;
            int h   = (u >> 3) & 1;
            int j   = u & 7;
            int co  = mt * 32 + i31;
            int ci  = ks * 16 + h * 8 + j;
            Wd[u] = (_Float16)Ws[((size_t)co * 64 + ci) * 9 + pos];
        }
    }
}

// ---------------------------------------------------------------------------
// conv core (ext rows): depth-2 weight pipeline over 3 LDS buffers with
// COUNTED vmcnt + raw s_barrier (T3/T4).  Iter p: issue stage p+2; compute
// pos p; then s_waitcnt vmcnt(2) (vmcnt(0) only at p=7) + s_barrier +
// sched_barrier(0).  vmcnt(2) lets the just-issued stage ride across the
// barrier while guaranteeing stage p+1 (issued one pos earlier; vmcnt
// retires in order) is complete.  ds_reads of pos p are all consumed by
// MFMAs (lgkmcnt-forced) before the barrier, so distance-3 buffer reuse is
// safe.  Replaces 8 full __syncthreads drains (~200-500cyc each at
// 2 blocks/CU) with near-free counted waits.
// X fragments from the XOR-swizzled Xs tile:
//   elem(row, x, c8) at (row*66+x)*64 + (c8 ^ (x&7))*8   (halves)
// ---------------------------------------------------------------------------
template<int MODE>
__device__ __forceinline__ void conv_core(
    const _Float16* __restrict__ Xs, _Float16* __restrict__ Wl,
    const _Float16* __restrict__ Wg, int w, int i31, int h, int t,
    floatx16 (&acc)[2][2])
{
    int xsw[3], xbase[3];
#pragma unroll
    for (int kx = 0; kx < 3; ++kx) {
        int x = i31 + kx;
        xsw[kx]   = x & 7;
        xbase[kx] = x * 64;
    }
    const int rowb  = w * (66 * 64);
    const int wv    = t >> 6, l = t & 63;
    const int wfrag = i31 * 16 + h * 8;

#pragma unroll
    for (int p = 0; p < 9; ++p) {
        // stage pos p+2 into buf[(p+2)%3] (2 x 1KB chunks per wave)
        if (p + 2 < 9) {
#pragma unroll
            for (int j = 0; j < 2; ++j) {
                int ch = wv * 2 + j;
                gl_lds16(Wg + (p + 2) * 4096 + ch * 512 + l * 8,
                         Wl + ((p + 2) % 3) * 4096 + ch * 512);
            }
        }
        const int ky = p / 3, kx = p - ky * 3;
        const _Float16* wb = Wl + (p % 3) * 4096 + wfrag;
        half8_t fw0[4], fw1[4], fx0[4], fx1[4];
#pragma unroll
        for (int ks = 0; ks < 4; ++ks) {
            fw0[ks] = *(const half8_t*)(wb + ks * 512);
            fw1[ks] = *(const half8_t*)(wb + ks * 512 + 2048);
            const int c8  = ks * 2 + h;
            const int off = rowb + ky * (66 * 64) + xbase[kx] + ((c8 ^ xsw[kx]) * 8);
            fx0[ks] = *(const half8_t*)(Xs + off);
            fx1[ks] = *(const half8_t*)(Xs + off + 32 * 64);
        }
        __builtin_amdgcn_s_setprio(1);
#pragma unroll
        for (int ks = 0; ks < 4; ++ks) {
            if (MODE == 1) {
                acc[0][0] = __builtin_amdgcn_mfma_f32_32x32x16_f16(fx0[ks], fw0[ks], acc[0][0], 0, 0, 0);
                acc[0][1] = __builtin_amdgcn_mfma_f32_32x32x16_f16(fx0[ks], fw1[ks], acc[0][1], 0, 0, 0);
                acc[1][0] = __builtin_amdgcn_mfma_f32_32x32x16_f16(fx1[ks], fw0[ks], acc[1][0], 0, 0, 0);
                acc[1][1] = __builtin_amdgcn_mfma_f32_32x32x16_f16(fx1[ks], fw1[ks], acc[1][1], 0, 0, 0);
            } else {
                acc[0][0] = __builtin_amdgcn_mfma_f32_32x32x16_f16(fw0[ks], fx0[ks], acc[0][0], 0, 0, 0);
                acc[0][1] = __builtin_amdgcn_mfma_f32_32x32x16_f16(fw0[ks], fx1[ks], acc[0][1], 0, 0, 0);
                acc[1][0] = __builtin_amdgcn_mfma_f32_32x32x16_f16(fw1[ks], fx0[ks], acc[1][0], 0, 0, 0);
                acc[1][1] = __builtin_amdgcn_mfma_f32_32x32x16_f16(fw1[ks], fx1[ks], acc[1][1], 0, 0, 0);
            }
        }
        __builtin_amdgcn_s_setprio(0);
        if (p + 1 < 9) {
            if (p + 2 < 9) asm volatile("s_waitcnt vmcnt(2)" ::: "memory");
            else           asm volatile("s_waitcnt vmcnt(0)" ::: "memory");
            __builtin_amdgcn_s_barrier();
            __builtin_amdgcn_sched_barrier(0);
        }
    }
}

// ---------------------------------------------------------------------------
// MFMA implicit-GEMM conv, merged grid: (5, 24, 4) = 480 blocks <= 512
// capacity (2 blocks/CU @ 75 KB LDS) -> single dispatch wave.
// Phase 1 (all blocks): ext rows rg*4+w -> OutE.
// Phase 2 (rg<16): one top row tr=rg -> OutT (wave 0, weights preloaded).
// MODE 1: D[m=x][n=co] -> [b][OH][320][64];  MODE 2: D[m=co][n=x].
// ---------------------------------------------------------------------------
template<int MODE>
__global__ __launch_bounds__(256, 2) void conv_kernel(
    const _Float16* __restrict__ Xt, const _Float16* __restrict__ Wfl,
    _Float16* __restrict__ OutE, _Float16* __restrict__ OutT, ShiftInfo si)
{
    __shared__ __align__(16) _Float16 Xs[6 * 66 * 64];
    __shared__ __align__(16) _Float16 Wl[3 * 4096];
    const int xt = blockIdx.x, rg = blockIdx.y, b = blockIdx.z;
    const int x0 = xt * 64;
    const int t  = threadIdx.x;
    const int wv = t >> 6, l = t & 63;
    const int i31 = l & 31, h = l >> 5;

    int grow[6];
#pragma unroll
    for (int r = 0; r < 6; ++r) grow[r] = rg * 4 + r;   // grow[4],grow[5] may be 96,97 at rg=23

    // weight pos0+pos1 stage (completed by the prologue __syncthreads drain)
    {
#pragma unroll
        for (int pp = 0; pp < 2; ++pp)
#pragma unroll
            for (int j = 0; j < 2; ++j) {
                int ch = wv * 2 + j;
                gl_lds16(Wfl + pp * 4096 + ch * 512 + l * 8,
                         Wl + pp * 4096 + ch * 512);
            }
    }

    // interior: 48 chunks (6 rows x 8 chunks of 8 x-groups), 12 per wave.
    // Pre-swizzled global source: lane l loads logical c8=(l&7)^(x&7) so the
    // LINEAR LDS write lands data where the swizzled reader expects it.
    {
#pragma unroll
        for (int j = 0; j < 12; ++j) {
            int k = wv + 4 * j;         // 0..47
            int r = k >> 3, c = k & 7;
            if ((unsigned)grow[r] < HH) {
                int x  = 1 + 8 * c + (l >> 3);       // 1..64 (always in-image)
                int c8 = (l & 7) ^ (x & 7);
                const _Float16* g =
                    &Xt[((size_t)(b * HH + grow[r]) * WW + (x0 - 1 + x)) * 64 + c8 * 8];
                gl_lds16(g, &Xs[(r * 66 + 1 + 8 * c) * 64]);
            }
        }
    }

    // zero-fill rows that are out of image (only rg==23: rows 4,5)
#pragma unroll
    for (int r = 0; r < 6; ++r) {
        if ((unsigned)grow[r] >= HH) {
            for (int u = t; u < 66 * 8; u += 256) {
                float4 zz = make_float4(0.f, 0.f, 0.f, 0.f);
                *(float4*)&Xs[r * (66 * 64) + u * 8] = zz;
            }
        }
    }

    // halo x=0 and x=65 (bounds-checked scalar path, 96 threads)
    if (t < 96) {
        int r  = t >> 4, hx = (t >> 3) & 1, c8 = t & 7;
        int x  = hx ? 65 : 0;
        int gx = x0 - 1 + x;
        float4 v = make_float4(0.f, 0.f, 0.f, 0.f);
        if ((unsigned)grow[r] < HH && (unsigned)gx < WW)
            v = *(const float4*)&Xt[((size_t)(b * HH + grow[r]) * WW + gx) * 64 + c8 * 8];
        *(float4*)&Xs[(r * 66 + x) * 64 + ((c8 ^ (x & 7)) * 8)] = v;
    }
    __syncthreads();

    floatx16 acc[2][2];
#pragma unroll
    for (int a = 0; a < 2; ++a)
#pragma unroll
        for (int c = 0; c < 2; ++c)
            acc[a][c] = (floatx16){0.f,0.f,0.f,0.f, 0.f,0.f,0.f,0.f,
                                   0.f,0.f,0.f,0.f, 0.f,0.f,0.f,0.f};

    conv_core<MODE>(Xs, Wl, Wfl, wv, i31, h, t, acc);

    // phase-1 epilogue: ext rows -> OutE
    {
        const int om = rg * 4 + wv;
#pragma unroll
        for (int a = 0; a < 2; ++a)
#pragma unroll
            for (int c = 0; c < 2; ++c)
#pragma unroll
                for (int r = 0; r < 16; ++r) {
                    int dm = (r & 3) + 8 * (r >> 2) + 4 * h;
                    if (MODE == 1) {
                        int x  = x0 + a * 32 + dm;
                        int co = c * 32 + i31;
                        OutE[((size_t)(b * HH + om) * WW + x) * 64 + co] = (_Float16)acc[a][c][r];
                    } else {
                        int co = a * 32 + dm;
                        int x  = x0 + c * 32 + i31;
                        OutE[((size_t)(b * 64 + co) * HH + om) * WW + x] = (_Float16)acc[a][c][r];
                    }
                }
    }

    // ---------------- phase 2: one top row for rg<16 ----------------
    if (rg < 16) {
        const int tr = rg;
        const int trow = si.rows[tr];            // always in [0,95]
        __syncthreads();                         // all waves done reading Xs

        // wave 0 preloads the 24 weight fragments for pos 0..2 (L2-resident)
        half8_t fwp0[12], fwp1[12];
        if (wv == 0) {
#pragma unroll
            for (int p = 0; p < 3; ++p)
#pragma unroll
                for (int ks = 0; ks < 4; ++ks) {
                    const _Float16* wp = Wfl + p * 4096 + ks * 512 + i31 * 16 + h * 8;
                    fwp0[p * 4 + ks] = *(const half8_t*)(wp);
                    fwp1[p * 4 + ks] = *(const half8_t*)(wp + 2048);
                }
        }

        // stage row trow into Xs row 0: interior 8 chunks (2 per wave)
#pragma unroll
        for (int j = 0; j < 2; ++j) {
            int c = wv * 2 + j;                  // 0..7
            int x = 1 + 8 * c + (l >> 3);
            int c8 = (l & 7) ^ (x & 7);
            gl_lds16(&Xt[((size_t)(b * HH + trow) * WW + (x0 - 1 + x)) * 64 + c8 * 8],
                     &Xs[(1 + 8 * c) * 64]);
        }
        // halo x=0 / x=65
        if (t < 16) {
            int hx = t >> 3, c8 = t & 7;
            int x  = hx ? 65 : 0;
            int gx = x0 - 1 + x;
            float4 v = make_float4(0.f, 0.f, 0.f, 0.f);
            if ((unsigned)gx < WW)
                v = *(const float4*)&Xt[((size_t)(b * HH + trow) * WW + gx) * 64 + c8 * 8];
            *(float4*)&Xs[x * 64 + ((c8 ^ (x & 7)) * 8)] = v;
        }
        __syncthreads();                         // staging drained

        if (wv == 0) {
            floatx16 a2[2][2];
#pragma unroll
            for (int a = 0; a < 2; ++a)
#pragma unroll
                for (int c = 0; c < 2; ++c)
                    a2[a][c] = (floatx16){0.f,0.f,0.f,0.f, 0.f,0.f,0.f,0.f,
                                          0.f,0.f,0.f,0.f, 0.f,0.f,0.f,0.f};
#pragma unroll
            for (int p = 0; p < 3; ++p) {
                const int kx = p;
                const int x = i31 + kx;
#pragma unroll
                for (int ks = 0; ks < 4; ++ks) {
                    const int c8  = ks * 2 + h;
                    const int off = x * 64 + ((c8 ^ (x & 7)) * 8);
                    half8_t fx0v = *(const half8_t*)(Xs + off);
                    half8_t fx1v = *(const half8_t*)(Xs + off + 32 * 64);
                    half8_t w0 = fwp0[p * 4 + ks], w1 = fwp1[p * 4 + ks];
                    if (MODE == 1) {
                        a2[0][0] = __builtin_amdgcn_mfma_f32_32x32x16_f16(fx0v, w0, a2[0][0], 0, 0, 0);
                        a2[0][1] = __builtin_amdgcn_mfma_f32_32x32x16_f16(fx0v, w1, a2[0][1], 0, 0, 0);
                        a2[1][0] = __builtin_amdgcn_mfma_f32_32x32x16_f16(fx1v, w0, a2[1][0], 0, 0, 0);
                        a2[1][1] = __builtin_amdgcn_mfma_f32_32x32x16_f16(fx1v, w1, a2[1][1], 0, 0, 0);
                    } else {
                        a2[0][0] = __builtin_amdgcn_mfma_f32_32x32x16_f16(w0, fx0v, a2[0][0], 0, 0, 0);
                        a2[0][1] = __builtin_amdgcn_mfma_f32_32x32x16_f16(w0, fx1v, a2[0][1], 0, 0, 0);
                        a2[1][0] = __builtin_amdgcn_mfma_f32_32x32x16_f16(w1, fx0v, a2[1][0], 0, 0, 0);
                        a2[1][1] = __builtin_amdgcn_mfma_f32_32x32x16_f16(w1, fx1v, a2[1][1], 0, 0, 0);
                    }
                }
            }
#pragma unroll
            for (int a = 0; a < 2; ++a)
#pragma unroll
                for (int c = 0; c < 2; ++c)
#pragma unroll
                    for (int r = 0; r < 16; ++r) {
                        int dm = (r & 3) + 8 * (r >> 2) + 4 * h;
                        if (MODE == 1) {
                            int x  = x0 + a * 32 + dm;
                            int co = c * 32 + i31;
                            OutT[((size_t)(b * 16 + tr) * WW + x) * 64 + co] = (_Float16)a2[a][c][r];
                        } else {
                            int co = a * 32 + dm;
                            int x  = x0 + c * 32 + i31;
                            OutT[((size_t)(b * 64 + co) * 16 + tr) * WW + x] = (_Float16)a2[a][c][r];
                        }
                    }
        }
    }
}

// ---------------------------------------------------------------------------
// blend1: C[b][96][320][64] + T[b][16][320][64] -> Xt2[b][96][320][64] (f16)
// x-tile = 1 column: grid (320 xt, 4 b), block 256 = 8 co8 x 32 yt.
// LDS layout bank-swizzled via CSW (conflict-free reads; was 8-way).
// ---------------------------------------------------------------------------
__global__ __launch_bounds__(256) void blend1_kernel(
    const _Float16* __restrict__ Cb, const _Float16* __restrict__ T,
    const float* __restrict__ bias, _Float16* __restrict__ Xt2, ShiftInfo si)
{
    __shared__ __align__(16) _Float16 Cs[96 * 64];   // [row][co] 12.3 KB
    __shared__ __align__(16) _Float16 Ts[16 * 64];   // 2 KB
    const int x0 = blockIdx.x, b = blockIdx.y, t = threadIdx.x;
    const half8_t z = {0,0,0,0,0,0,0,0};

    {
        const int w = t >> 6, l = t & 63;
        const int c8s = (l & 7) ^ ((l >> 3) & 7);    // = (l&7) ^ (row&7)
#pragma unroll
        for (int j = 0; j < 3; ++j) {
            int k = w + 4 * j;                   // 0..11, 8 rows each
            int row = 8 * k + (l >> 3);
            gl_lds16(&Cb[((size_t)(b * HH + row) * WW + x0) * 64 + c8s * 8],
                     &Cs[k * 512]);
        }
        if (w < 2) {
            int row = 8 * w + (l >> 3);
            gl_lds16(&T[((size_t)(b * 16 + row) * WW + x0) * 64 + c8s * 8],
                     &Ts[w * 512]);
        }
    }
    __syncthreads();

    const int co8 = t & 7, yt = t >> 3;
    half8_t bv;
#pragma unroll
    for (int j = 0; j < 8; ++j) bv[j] = (_Float16)bias[co8 * 8 + j];

    const int y0 = yt * 3;
    half8_t cur[NP];
#pragma unroll
    for (int d = 0; d < NP; ++d) {
        int r = y0 + si.s0[d] - 1;
        cur[d] = (r < HH) ? *(const half8_t*)&Cs[CSW(r, co8)] : z;
    }
    for (int y = y0; y < y0 + 3; ++y) {
        half8_t m = z;
#pragma unroll
        for (int d = 0; d < NP; ++d) {
            int r1 = y + si.s0[d];
            half8_t v1 = (r1 < HH) ? *(const half8_t*)&Cs[CSW(r1, co8)] : z;
            half8_t v0 = cur[d];
            cur[d] = v1;
            _Float16 a = (_Float16)si.wa[d], wg = (_Float16)si.wb[d];
            half8_t p;
            if (y == 0) {
                half8_t t0 = *(const half8_t*)&Ts[CSW(2 * d, co8)];
                half8_t t1 = *(const half8_t*)&Ts[CSW(2 * d + 1, co8)];
                p = a * (v0 - t0) + wg * (v1 - t1);
            } else {
                p = a * v0 + wg * v1;
            }
            m = (d == 0) ? p : __builtin_elementwise_max(m, p);
        }
        half8_t o = __builtin_elementwise_max(m + bv, z);
        *(half8_t*)&Xt2[((size_t)(b * HH + y) * WW + x0) * 64 + co8 * 8] = o;
    }
}

// ---------------------------------------------------------------------------
// blend2: C[b][64][96][320] + T[b][64][16][320] -> Out fp32 [b][64][96][320]
// grid 1280 = (xt 5) x (co 64) x (b 4), block 256.
// LDS layout bank-swizzled via CSW (conflict-free reads; was 8-way).
// ---------------------------------------------------------------------------
__global__ __launch_bounds__(256) void blend2_kernel(
    const _Float16* __restrict__ Cb, const _Float16* __restrict__ T,
    const float* __restrict__ bias, float* __restrict__ Out, ShiftInfo si)
{
    __shared__ __align__(16) _Float16 Cs[96 * 64];
    __shared__ __align__(16) _Float16 Ts[16 * 64];
    const int task = blockIdx.x, t = threadIdx.x;
    const int xt = task % 5;
    const int rem = task / 5;
    const int co = rem & 63;
    const int b  = rem >> 6;
    const int x0 = xt * 64;
    const half8_t z = {0,0,0,0,0,0,0,0};

    {
        const int w = t >> 6, l = t & 63;
        const int x8s = (l & 7) ^ ((l >> 3) & 7);    // = (l&7) ^ (row&7)
#pragma unroll
        for (int j = 0; j < 3; ++j) {
            int k = w + 4 * j;                   // 0..11, 8 rows each
            int row = 8 * k + (l >> 3);
            gl_lds16(&Cb[((size_t)(b * 64 + co) * HH + row) * WW + x0 + x8s * 8],
                     &Cs[k * 512]);
        }
        if (w < 2) {
            int row = 8 * w + (l >> 3);
            gl_lds16(&T[((size_t)(b * 64 + co) * 16 + row) * WW + x0 + x8s * 8],
                     &Ts[w * 512]);
        }
    }
    __syncthreads();

    const int x8 = t & 7, yt = t >> 3;
    const float bvf = bias[co];
    const int y0 = yt * 3;

    half8_t cur[NP];
#pragma unroll
    for (int d = 0; d < NP; ++d) {
        int r = y0 + si.s0[d] - 1;
        cur[d] = (r < HH) ? *(const half8_t*)&Cs[CSW(r, x8)] : z;
    }
    for (int y = y0; y < y0 + 3; ++y) {
        half8_t m = z;
#pragma unroll
        for (int d = 0; d < NP; ++d) {
            int r1 = y + si.s0[d];
            half8_t v1 = (r1 < HH) ? *(const half8_t*)&Cs[CSW(r1, x8)] : z;
            half8_t v0 = cur[d];
            cur[d] = v1;
            _Float16 a = (_Float16)si.wa[d], wg = (_Float16)si.wb[d];
            half8_t p;
            if (y == 0) {
                half8_t t0 = *(const half8_t*)&Ts[CSW(2 * d, x8)];
                half8_t t1 = *(const half8_t*)&Ts[CSW(2 * d + 1, x8)];
                p = a * (v0 - t0) + wg * (v1 - t1);
            } else {
                p = a * v0 + wg * v1;
            }
            m = (d == 0) ? p : __builtin_elementwise_max(m, p);
        }
        float4 o0, o1;
        o0.x = fmaxf((float)m[0] + bvf, 0.f);
        o0.y = fmaxf((float)m[1] + bvf, 0.f);
        o0.z = fmaxf((float)m[2] + bvf, 0.f);
        o0.w = fmaxf((float)m[3] + bvf, 0.f);
        o1.x = fmaxf((float)m[4] + bvf, 0.f);
        o1.y = fmaxf((float)m[5] + bvf, 0.f);
        o1.z = fmaxf((float)m[6] + bvf, 0.f);
        o1.w = fmaxf((float)m[7] + bvf, 0.f);
        float* op = Out + ((size_t)(b * 64 + co) * HH + y) * WW + x0 + x8 * 8;
        *(float4*)op = o0;
        *(float4*)(op + 4) = o1;
    }
}

// ---------------------------------------------------------------------------
extern "C" void kernel_launch(void* const* d_in, const int* in_sizes, int n_in,
                              void* d_out, int out_size, void* d_ws, size_t ws_size,
                              hipStream_t stream) {
    const float* x  = (const float*)d_in[0];
    const float* W1 = (const float*)d_in[1];
    const float* b1 = (const float*)d_in[2];
    const float* W2 = (const float*)d_in[3];
    const float* b2 = (const float*)d_in[4];
    float* out = (float*)d_out;

    _Float16* Xt1 = (_Float16*)d_ws;            // 7,864,320 halves
    _Float16* Cb  = Xt1 + 7864320;              // 7,864,320
    _Float16* T   = Cb  + 7864320;              // 1,310,720
    _Float16* Wf  = T   + 1310720;              // 73,728 (both layers, MFMA layout)
    _Float16* Xt2 = (_Float16*)d_out;           // f16 scratch inside d_out

    ShiftInfo si;
    for (int d = 0; d < NP; ++d) {
        double disp = 0.02 + d * (0.98 / 7.0);
        double sh   = 76.0 * disp;
        int s0      = (int)floor(sh);
        double w    = sh - (double)s0;
        si.s0[d] = s0;
        si.wa[d] = (float)(1.0 - w);
        si.wb[d] = (float)w;
        si.rows[2 * d]     = s0 - 1;
        si.rows[2 * d + 1] = s0;
    }

    prep_kernel<<<dim3(786), 256, 0, stream>>>(x, W1, W2, Xt1, Wf);

    conv_kernel<1><<<dim3(5, 24, 4), 256, 0, stream>>>(Xt1, Wf, Cb, T, si);
    blend1_kernel<<<dim3(320, 4), 256, 0, stream>>>(Cb, T, b1, Xt2, si);

    conv_kernel<2><<<dim3(5, 24, 4), 256, 0, stream>>>(Xt2, Wf + 36864, Cb, T, si);
    blend2_kernel<<<dim3(1280), 256, 0, stream>>>(Cb, T, b2, out, si);
}